// Round 1
// baseline (92.203 us; speedup 1.0000x reference)
//
#include <hip/hip_runtime.h>

#define HH 512
#define DD 64
#define MROWS 32
#define TPB 512            // 8 waves: each owns 32 rows x 64 cols (2rt x 4ct)
#define LP 520             // u16 pitch for 32x512 LDS tiles

typedef unsigned short u16;
typedef short s16x8 __attribute__((ext_vector_type(8)));   // 8 bf16 = 4 VGPRs
typedef float f32x4 __attribute__((ext_vector_type(4)));

#define MFMA16(A,B,C) __builtin_amdgcn_mfma_f32_16x16x32_bf16((A),(B),(C),0,0,0)

// ---- workspace layout (u16 element offsets), fragment-linear:
//   addr = ntile*16*K + ks*512 + lane*8 ; value[j] = M[k = ks*32+(lane>>4)*8+j][n = nt*16+(lane&15)]
#define OFF_EF   0
#define OFF_W2F  (HH*HH)
#define OFF_W1F  (2*HH*HH)
#define OFF_W3F  (2*HH*HH + HH*DD)
#define OFF_Z0B  ((2*HH*HH + 2*HH*DD)*2)   // byte offset of z0 (f32[512])

__device__ __forceinline__ u16 f2bf(float f) {
    unsigned u = __builtin_bit_cast(unsigned, f);
    u += 0x7fffu + ((u >> 16) & 1u);
    return (u16)(u >> 16);
}
__device__ __forceinline__ float bf2f(u16 h) {
    return __builtin_bit_cast(float, (unsigned)h << 16);
}
__device__ __forceinline__ float fast_tanh(float x) {
    float e = __expf(2.0f * x);
    return 1.0f - 2.0f * __builtin_amdgcn_rcpf(e + 1.0f);
}

// =======================================================================
// precompute: 137 blocks x 256 threads (unchanged — ~4 us)
// =======================================================================
__global__ __launch_bounds__(256) void precompute(
    const float* __restrict__ t,  const float* __restrict__ W1,
    const float* __restrict__ b1, const float* __restrict__ W2,
    const float* __restrict__ W3, u16* __restrict__ ws16, float* __restrict__ z0)
{
    __shared__ float T[16 * 264 > 256 * 20 ? 16 * 264 : 256 * 20];
    u16* Ef  = ws16 + OFF_EF;
    u16* W2f = ws16 + OFF_W2F;
    u16* W1f = ws16 + OFF_W1F;
    u16* W3f = ws16 + OFF_W3F;

    const int bid = blockIdx.x, tid = threadIdx.x;
    const int lane = tid & 63, wv = tid >> 6;
    const int m16 = lane & 15, q = lane >> 4;

    if (bid < 64) {
        const int nt = bid >> 1, bh = bid & 1;
        const int a0 = nt * 16, b0 = bh * 256;
        s16x8 afh[2], afl[2];
#pragma unroll
        for (int h = 0; h < 2; ++h)
#pragma unroll
            for (int j = 0; j < 8; ++j) {
                int i = h * 32 + q * 8 + j;
                float v = W1[(1 + i) * HH + a0 + m16];
                u16 hi = f2bf(v);
                afh[h][j] = (short)hi;
                afl[h][j] = (short)f2bf(v - bf2f(hi));
            }
#pragma unroll
        for (int bt = 0; bt < 4; ++bt) {
            int bl = wv * 64 + bt * 16;
            s16x8 bfh[2], bfl[2];
#pragma unroll
            for (int h = 0; h < 2; ++h) {
                const float* src = W3 + (b0 + bl + m16) * DD + h * 32 + q * 8;
                float4 p0 = *(const float4*)(src);
                float4 p1 = *(const float4*)(src + 4);
                float vv[8] = {p0.x,p0.y,p0.z,p0.w,p1.x,p1.y,p1.z,p1.w};
#pragma unroll
                for (int j = 0; j < 8; ++j) {
                    u16 hi = f2bf(vv[j]);
                    bfh[h][j] = (short)hi;
                    bfl[h][j] = (short)f2bf(vv[j] - bf2f(hi));
                }
            }
            f32x4 c = {0.f, 0.f, 0.f, 0.f};
#pragma unroll
            for (int h = 0; h < 2; ++h) {
                c = MFMA16(afh[h], bfh[h], c);
                c = MFMA16(afh[h], bfl[h], c);
                c = MFMA16(afl[h], bfh[h], c);
            }
#pragma unroll
            for (int r = 0; r < 4; ++r)
                T[(4 * q + r) * 264 + bl + m16] = c[r];
        }
        __syncthreads();
#pragma unroll
        for (int p = 0; p < 2; ++p) {
            int ksl = p * 4 + wv;
            int al  = m16;
            int blc = ksl * 32 + q * 8;
            const float* w2p = W2 + (a0 + al) * HH + b0 + blc;
            float4 wa = *(const float4*)(w2p), wb = *(const float4*)(w2p + 4);
            const float* glp = T + al * 264 + blc;
            s16x8 o;
            o[0]=(short)f2bf(wa.x*glp[0]); o[1]=(short)f2bf(wa.y*glp[1]);
            o[2]=(short)f2bf(wa.z*glp[2]); o[3]=(short)f2bf(wa.w*glp[3]);
            o[4]=(short)f2bf(wb.x*glp[4]); o[5]=(short)f2bf(wb.y*glp[5]);
            o[6]=(short)f2bf(wb.z*glp[6]); o[7]=(short)f2bf(wb.w*glp[7]);
            *(s16x8*)(Ef + nt * 8192 + (b0 / 32 + ksl) * 512 + lane * 8) = o;
        }
        if (bh == 0 && tid < 128) {
            int ks = tid >> 6, ln = tid & 63;
            int n  = nt * 16 + (ln & 15);
            int k0 = ks * 32 + (ln >> 4) * 8;
            s16x8 o;
#pragma unroll
            for (int j = 0; j < 8; ++j) o[j] = (short)f2bf(W1[(1 + k0 + j) * HH + n]);
            *(s16x8*)(W1f + nt * 1024 + ks * 512 + ln * 8) = o;
        }
    } else if (bid < 128) {
        const int nt = (bid - 64) >> 1, kh = (bid - 64) & 1;
        const int n0 = nt * 16, k0 = kh * 256;
#pragma unroll
        for (int it = 0; it < 4; ++it) {
            int r = (tid >> 2) + it * 64;
            int c = (tid & 3) * 4;
            float4 v = *(const float4*)(W2 + (k0 + r) * HH + n0 + c);
            *(float4*)(T + r * 20 + c) = v;
        }
        __syncthreads();
#pragma unroll
        for (int p = 0; p < 2; ++p) {
            int ksl = p * 4 + wv;
            int kq  = ksl * 32 + q * 8;
            s16x8 o;
#pragma unroll
            for (int j = 0; j < 8; ++j) o[j] = (short)f2bf(T[(kq + j) * 20 + m16]);
            *(s16x8*)(W2f + nt * 8192 + (k0 / 32 + ksl) * 512 + lane * 8) = o;
        }
    } else if (bid < 136) {
        const int ot = (bid - 128) >> 1, kh = (bid - 128) & 1;
        const int o0 = ot * 16, k0 = kh * 256;
#pragma unroll
        for (int it = 0; it < 4; ++it) {
            int r = (tid >> 2) + it * 64;
            int c = (tid & 3) * 4;
            float4 v = *(const float4*)(W3 + (k0 + r) * DD + o0 + c);
            *(float4*)(T + r * 20 + c) = v;
        }
        __syncthreads();
#pragma unroll
        for (int p = 0; p < 2; ++p) {
            int ksl = p * 4 + wv;
            int kq  = ksl * 32 + q * 8;
            s16x8 o;
#pragma unroll
            for (int j = 0; j < 8; ++j) o[j] = (short)f2bf(T[(kq + j) * 20 + m16]);
            *(s16x8*)(W3f + ot * 8192 + (k0 / 32 + ksl) * 512 + lane * 8) = o;
        }
    } else {
        for (int n = tid; n < HH; n += 256)
            z0[n] = b1[n] + t[0] * W1[n];
    }
}

// =======================================================================
// cnf_main: 256 blocks x 512 threads (8 waves).
// Each wave owns 32 rows x 64 cols (2 rt x 4 ct): A-fragment reuse x4,
// VGPR cap 256 (launch_bounds 512,2) -> explicit depth-4 B prefetch and
// double-buffered A ds_reads. Phase 3 balanced across all 8 waves.
// =======================================================================
__global__ __launch_bounds__(TPB, 2) void cnf_main(
    const float* __restrict__ x,  const u16* __restrict__ ws16,
    const float* __restrict__ z0, const float* __restrict__ b2,
    const float* __restrict__ b3, float* __restrict__ out)
{
    __shared__ u16 h1s[MROWS * LP];
    __shared__ u16 h2s[MROWS * LP];
    __shared__ u16 d2s[MROWS * LP];     // low region doubles as xs before phase 2
    __shared__ float z0s[HH];
    __shared__ float b2s[HH];
    __shared__ float b3s[DD];
    __shared__ float divacc[8][MROWS];

    const u16* Ef  = ws16 + OFF_EF;
    const u16* W2f = ws16 + OFF_W2F;
    const u16* W1f = ws16 + OFF_W1F;
    const u16* W3f = ws16 + OFF_W3F;

    const int tid  = threadIdx.x;
    const int lane = tid & 63;
    const int w    = tid >> 6;        // 8 waves
    const int m16  = lane & 15;
    const int q    = lane >> 4;
    const int kq   = q * 8;
    const int r0   = blockIdx.x * MROWS;

    // decorrelation keys: co-XCD blocks (stride 8 under round-robin) differ
    const int noff = (blockIdx.x >> 3) & 31;
    const int koff = (blockIdx.x >> 3) & 15;

    // wave's four n-tiles (a permutation of 0..31 across (w,ct))
    int tile[4];
#pragma unroll
    for (int ct = 0; ct < 4; ++ct) tile[ct] = (4 * w + ct + noff) & 31;

    u16* xs = d2s;                    // overlap: xs dead after phase 1

    // ---- top-of-kernel global prefetch: W1f frags + W2f depth-4 ----
    s16x8 p1b[4][2];
#pragma unroll
    for (int ct = 0; ct < 4; ++ct) {
        const u16* bb = W1f + tile[ct] * 1024 + lane * 8;
        p1b[ct][0] = *(const s16x8*)(bb);
        p1b[ct][1] = *(const s16x8*)(bb + 512);
    }
    const u16* w2bp[4];
#pragma unroll
    for (int ct = 0; ct < 4; ++ct) w2bp[ct] = W2f + tile[ct] * 8192 + lane * 8;
    s16x8 Bv[4][4];                   // [slot][ct], rolling depth-4
#pragma unroll
    for (int k = 0; k < 4; ++k) {
        const int kk = (koff + k) & 15;
#pragma unroll
        for (int ct = 0; ct < 4; ++ct)
            Bv[k][ct] = *(const s16x8*)(w2bp[ct] + kk * 512);
    }

    // ---- stage ----
    for (int idx = tid; idx < MROWS * DD; idx += TPB) {
        int r = idx >> 6, c = idx & 63;
        xs[r * 72 + c] = f2bf(x[(r0 + r) * (DD + 1) + c]);
    }
    if (tid < HH) { z0s[tid] = z0[tid]; b2s[tid] = b2[tid]; }
    if (tid < DD) b3s[tid] = b3[tid];
    __syncthreads();

    float d1reg[2][4][4];             // d1 = 1-h1^2, kept in regs for phase 4

    // ---- phase 1: h1 = tanh([t,x]@W1 + z0), K=64 ----
    {
        s16x8 xa[2][2];
#pragma unroll
        for (int rt = 0; rt < 2; ++rt)
#pragma unroll
            for (int h = 0; h < 2; ++h)
                xa[rt][h] = *(const s16x8*)(xs + (rt * 16 + m16) * 72 + h * 32 + kq);
#pragma unroll
        for (int ct = 0; ct < 4; ++ct) {
            const int col = tile[ct] * 16 + m16;
            const float zc = z0s[col];
#pragma unroll
            for (int rt = 0; rt < 2; ++rt) {
                f32x4 c = {0.f, 0.f, 0.f, 0.f};
                c = MFMA16(xa[rt][0], p1b[ct][0], c);
                c = MFMA16(xa[rt][1], p1b[ct][1], c);
#pragma unroll
                for (int i = 0; i < 4; ++i) {
                    float hv = fast_tanh(c[i] + zc);
                    h1s[(rt * 16 + 4 * q + i) * LP + col] = f2bf(hv);
                    d1reg[rt][ct][i] = 1.0f - hv * hv;
                }
            }
        }
    }
    __syncthreads();

    // ---- phase 2: h2 = tanh(h1@W2 + b2); A double-buffered, B depth-4 ----
    f32x4 acc[2][4];
#pragma unroll
    for (int rt = 0; rt < 2; ++rt)
#pragma unroll
        for (int ct = 0; ct < 4; ++ct) acc[rt][ct] = (f32x4){0.f,0.f,0.f,0.f};
    {
        const u16* ap0 = h1s + m16 * LP + kq;
        const u16* ap1 = h1s + (16 + m16) * LP + kq;
        s16x8 Aq[2][2];               // [parity][rt]
        {
            const int kk0 = koff & 15;
            Aq[0][0] = *(const s16x8*)(ap0 + kk0 * 32);
            Aq[0][1] = *(const s16x8*)(ap1 + kk0 * 32);
        }
#pragma unroll
        for (int ks = 0; ks < 16; ++ks) {
            const int sl = ks & 3, cur = ks & 1;
            if (ks < 15) {
                const int kn = (koff + ks + 1) & 15;
                Aq[cur ^ 1][0] = *(const s16x8*)(ap0 + kn * 32);
                Aq[cur ^ 1][1] = *(const s16x8*)(ap1 + kn * 32);
            }
#pragma unroll
            for (int ct = 0; ct < 4; ++ct) {
                acc[0][ct] = MFMA16(Aq[cur][0], Bv[sl][ct], acc[0][ct]);
                acc[1][ct] = MFMA16(Aq[cur][1], Bv[sl][ct], acc[1][ct]);
            }
            if (ks < 12) {
                const int kn = (koff + ks + 4) & 15;
#pragma unroll
                for (int ct = 0; ct < 4; ++ct)
                    Bv[sl][ct] = *(const s16x8*)(w2bp[ct] + kn * 512);
            }
        }
    }

    // ---- issue phase-4 Ef preloads (slots 0,1) before epilogue/barrier ----
    const u16* efp[4];
#pragma unroll
    for (int ct = 0; ct < 4; ++ct) efp[ct] = Ef + tile[ct] * 8192 + lane * 8;
    s16x8 Ev[4][4];                   // [slot][ct]
#pragma unroll
    for (int k = 0; k < 2; ++k) {
        const int kk = (koff + k) & 15;
#pragma unroll
        for (int ct = 0; ct < 4; ++ct)
            Ev[k][ct] = *(const s16x8*)(efp[ct] + kk * 512);
    }

    // ---- phase-2 epilogue: tanh -> h2s, d2 -> d2s ----
#pragma unroll
    for (int rt = 0; rt < 2; ++rt)
#pragma unroll
        for (int ct = 0; ct < 4; ++ct) {
            const int col = tile[ct] * 16 + m16;
            const float bc = b2s[col];
#pragma unroll
            for (int i = 0; i < 4; ++i) {
                int row = rt * 16 + 4 * q + i;
                float hv = fast_tanh(acc[rt][ct][i] + bc);
                h2s[row * LP + col] = f2bf(hv);
                d2s[row * LP + col] = f2bf(1.0f - hv * hv);
            }
        }
    __syncthreads();

    // ---- phase 3 (all 8 waves, one 16x16 tile each): dx = h2@W3 + b3 ----
    {
        const int rowt = w >> 2;
        const int ot   = (w + noff) & 3;
        const u16* ap = h2s + (rowt * 16 + m16) * LP + kq;
        const u16* bp = W3f + ot * 8192 + lane * 8;
        s16x8 W3r[4];
#pragma unroll
        for (int k = 0; k < 4; ++k)
            W3r[k] = *(const s16x8*)(bp + ((koff + k) & 15) * 512);
        f32x4 cA = {0.f,0.f,0.f,0.f}, cB = {0.f,0.f,0.f,0.f};
#pragma unroll
        for (int ks = 0; ks < 16; ++ks) {
            const int kk = (koff + ks) & 15;
            s16x8 f = *(const s16x8*)(ap + kk * 32);
            const int sl = ks & 3;
            if (ks & 1) cB = MFMA16(f, W3r[sl], cB);
            else        cA = MFMA16(f, W3r[sl], cA);
            if (ks < 12) W3r[sl] = *(const s16x8*)(bp + ((koff + ks + 4) & 15) * 512);
        }
        f32x4 c3 = cA + cB;
        const int o = ot * 16 + m16;
#pragma unroll
        for (int i = 0; i < 4; ++i)
            out[(r0 + rowt * 16 + 4 * q + i) * (DD + 1) + o] = c3[i] + b3s[o];
    }

    // ---- phase 4 (all 8 waves): M = d2@Ef; div = sum d1 .* M ----
    {
        f32x4 g[2][4];
#pragma unroll
        for (int rt = 0; rt < 2; ++rt)
#pragma unroll
            for (int ct = 0; ct < 4; ++ct) g[rt][ct] = (f32x4){0.f,0.f,0.f,0.f};

        // fill Ef slots 2,3
#pragma unroll
        for (int k = 2; k < 4; ++k) {
            const int kk = (koff + k) & 15;
#pragma unroll
            for (int ct = 0; ct < 4; ++ct)
                Ev[k][ct] = *(const s16x8*)(efp[ct] + kk * 512);
        }
        const u16* dp0 = d2s + m16 * LP + kq;
        const u16* dp1 = d2s + (16 + m16) * LP + kq;
        s16x8 Aq[2][2];
        {
            const int kk0 = koff & 15;
            Aq[0][0] = *(const s16x8*)(dp0 + kk0 * 32);
            Aq[0][1] = *(const s16x8*)(dp1 + kk0 * 32);
        }
#pragma unroll
        for (int ks = 0; ks < 16; ++ks) {
            const int sl = ks & 3, cur = ks & 1;
            if (ks < 15) {
                const int kn = (koff + ks + 1) & 15;
                Aq[cur ^ 1][0] = *(const s16x8*)(dp0 + kn * 32);
                Aq[cur ^ 1][1] = *(const s16x8*)(dp1 + kn * 32);
            }
#pragma unroll
            for (int ct = 0; ct < 4; ++ct) {
                g[0][ct] = MFMA16(Aq[cur][0], Ev[sl][ct], g[0][ct]);
                g[1][ct] = MFMA16(Aq[cur][1], Ev[sl][ct], g[1][ct]);
            }
            if (ks < 12) {
                const int kn = (koff + ks + 4) & 15;
#pragma unroll
                for (int ct = 0; ct < 4; ++ct)
                    Ev[sl][ct] = *(const s16x8*)(efp[ct] + kn * 512);
            }
        }
#pragma unroll
        for (int rt = 0; rt < 2; ++rt)
#pragma unroll
            for (int i = 0; i < 4; ++i) {
                float v = d1reg[rt][0][i] * g[rt][0][i]
                        + d1reg[rt][1][i] * g[rt][1][i]
                        + d1reg[rt][2][i] * g[rt][2][i]
                        + d1reg[rt][3][i] * g[rt][3][i];
                v += __shfl_xor(v, 1, 64);
                v += __shfl_xor(v, 2, 64);
                v += __shfl_xor(v, 4, 64);
                v += __shfl_xor(v, 8, 64);
                if (m16 == 0) divacc[w][rt * 16 + 4 * q + i] = v;
            }
    }
    __syncthreads();

    if (tid < MROWS) {
        float s = 0.0f;
#pragma unroll
        for (int ww = 0; ww < 8; ++ww) s += divacc[ww][tid];
        out[(r0 + tid) * (DD + 1) + DD] = s;
    }
}

extern "C" void kernel_launch(void* const* d_in, const int* in_sizes, int n_in,
                              void* d_out, int out_size, void* d_ws, size_t ws_size,
                              hipStream_t stream) {
    const float* t  = (const float*)d_in[0];
    const float* x  = (const float*)d_in[1];
    const float* W1 = (const float*)d_in[2];
    const float* b1 = (const float*)d_in[3];
    const float* W2 = (const float*)d_in[4];
    const float* b2 = (const float*)d_in[5];
    const float* W3 = (const float*)d_in[6];
    const float* b3 = (const float*)d_in[7];
    float* out = (float*)d_out;

    u16*   ws16 = (u16*)d_ws;
    float* z0   = (float*)((char*)d_ws + OFF_Z0B);

    precompute<<<137, 256, 0, stream>>>(t, W1, b1, W2, W3, ws16, z0);
    cnf_main<<<8192 / MROWS, TPB, 0, stream>>>(x, ws16, z0, b2, b3, out);
}